// Round 15
// baseline (132.795 us; speedup 1.0000x reference)
//
#include <hip/hip_runtime.h>
#include <stdint.h>

#define BB 4
#define NN 2000
#define K_PRE 1000
#define KPAD 1024
#define MAXOUT 128
#define NMS_THR 0.3f
#define MASK_IN_VOX (28*28*28)   // 21952
#define MASK_OUT_VOX (32*32*32)  // 32768

typedef float f4 __attribute__((ext_vector_type(4)));   // nontemporal-compatible

// ---------------- rank (stable descending argsort) + regression -------------
__global__ __launch_bounds__(256) void rank_kernel(const float* __restrict__ scores,
                                                   const float* __restrict__ proposals,
                                                   const float* __restrict__ deltas,
                                                   int* __restrict__ order,
                                                   float* __restrict__ boxes_ws) {
    int b = blockIdx.x >> 5;
    int blk = blockIdx.x & 31;
    __shared__ float s[NN];
    const float* sb = scores + b * NN;
    for (int u = threadIdx.x; u < NN / 4; u += 256)
        ((float4*)s)[u] = ((const float4*)sb)[u];
    __syncthreads();

    int i = blk * 64 + (threadIdx.x >> 2);
    int q = threadIdx.x & 3;
    float si = (i < NN) ? s[i] : 0.f;
    int cnt = 0;
    int j0 = q * 500;
    const float4* s4 = (const float4*)s;
#pragma unroll 5
    for (int u = 0; u < 125; ++u) {
        float4 v = s4[j0 / 4 + u];
        int j = j0 + u * 4;
        cnt += (v.x > si) + (v.y > si) + (v.z > si) + (v.w > si);
        cnt += ((v.x == si) & (j + 0 < i)) + ((v.y == si) & (j + 1 < i))
             + ((v.z == si) & (j + 2 < i)) + ((v.w == si) & (j + 3 < i));
    }
    cnt += __shfl_xor(cnt, 1);
    cnt += __shfl_xor(cnt, 2);

    if (q == 0 && i < NN && cnt < K_PRE) {
        int rank = cnt;
        order[b * KPAD + rank] = i;
        const float* p = proposals + (size_t)(b * NN + i) * 6;
        const float* d = deltas    + (size_t)(b * NN + i) * 6;
        float py1 = p[0], px1 = p[1], pz1 = p[2], py2 = p[3], px2 = p[4], pz2 = p[5];
        float h = py2 - py1, w = px2 - px1, dd = pz2 - pz1;
        float cy = py1 + 0.5f * h + d[0] * h;
        float cx = px1 + 0.5f * w + d[1] * w;
        float cz = pz1 + 0.5f * dd + d[2] * dd;
        h *= expf(d[3]); w *= expf(d[4]); dd *= expf(d[5]);
        float* bw = boxes_ws + (size_t)b * 6 * KPAD + rank;
        bw[0 * KPAD] = cy - 0.5f * h;  bw[1 * KPAD] = cx - 0.5f * w;  bw[2 * KPAD] = cz - 0.5f * dd;
        bw[3 * KPAD] = cy + 0.5f * h;  bw[4 * KPAD] = cx + 0.5f * w;  bw[5 * KPAD] = cz + 0.5f * dd;
    }
}

// ---------------- suppression bit-matrix build ------------------------------
// rowBits[(b*KPAD+k)*64+l] (uint16): bit w <=> IoU(box k, box 64w+l) > thr
__global__ __launch_bounds__(256) void build_kernel(const float* __restrict__ boxes_ws,
                                                    unsigned short* __restrict__ rowBits) {
    int b = blockIdx.y;
    int kbase = blockIdx.x * 16;
    __shared__ float sbx[6][1088];     // stride-17 padding: index k + (k>>4)
    int tid = threadIdx.x;
    const float* bw = boxes_ws + (size_t)b * 6 * KPAD;
    for (int k = tid; k < KPAD; k += 256) {
        int ks = k + (k >> 4);
#pragma unroll
        for (int c = 0; c < 6; ++c) sbx[c][ks] = bw[c * KPAD + k];
    }
    __syncthreads();
    int l = tid & 63, lr = tid >> 6;
#pragma unroll
    for (int pss = 0; pss < 4; ++pss) {
        int k = kbase + pss * 4 + lr;
        int ks = k + (k >> 4);
        float ry1 = sbx[0][ks], rx1 = sbx[1][ks], rz1 = sbx[2][ks];
        float ry2 = sbx[3][ks], rx2 = sbx[4][ks], rz2 = sbx[5][ks];
        float v1 = (ry2 - ry1) * (rx2 - rx1) * (rz2 - rz1);
        uint32_t bits = 0;
#pragma unroll
        for (int w = 0; w < 16; ++w) {
            int j = 64 * w + l;
            int js = j + (j >> 4);
            float y1 = sbx[0][js], x1 = sbx[1][js], z1 = sbx[2][js];
            float y2 = sbx[3][js], x2 = sbx[4][js], z2 = sbx[5][js];
            float iy = fmaxf(fminf(ry2, y2) - fmaxf(ry1, y1), 0.f);
            float ix = fmaxf(fminf(rx2, x2) - fmaxf(rx1, x1), 0.f);
            float iz = fmaxf(fminf(rz2, z2) - fmaxf(rz1, z1), 0.f);
            float inter = iy * ix * iz;
            float v2 = (y2 - y1) * (x2 - x1) * (z2 - z1);
            float iou = inter / (v1 + v2 - inter + 1e-8f);
            bits |= (iou > NMS_THR ? 1u : 0u) << w;
        }
        if (k < K_PRE)
            rowBits[((size_t)(b * KPAD + k)) * 64 + l] = (unsigned short)bits;
    }
}

// ---------------- fused walk+resize (R12-proven) + nt streams + setprio -----
__global__ __launch_bounds__(256) void resize_walk_kernel(
        const float* __restrict__ masks,
        const unsigned short* __restrict__ rowBits,
        const int* __restrict__ order,
        const float* __restrict__ boxes_ws,
        float* __restrict__ out_boxes,
        float* __restrict__ out_masks,
        float* __restrict__ out_bidx) {
    int s = blockIdx.x;            // 0..511
    int b = s >> 7;
    int sl = s & 127;              // which pick this block owns
    int tid = threadIdx.x;

    __shared__ int   res_k;
    __shared__ float res_vf;
    __shared__ __align__(16) float rowbuf[4][64 * 36];

    if (tid < 64) {
        __builtin_amdgcn_s_setprio(1);           // latency-critical serial chain
        int lane = tid;
        const unsigned short* rowB = rowBits + (size_t)b * KPAD * 64;
        uint32_t sup = (lane >= 40) ? (1u << 15) : 0u;   // pads >=1000 pre-suppressed
        int nsel = 0, kmine = 0, got = 0;

        auto ROW = [&](int g) -> unsigned short {
            return rowB[((size_t)g << 6) + lane];        // L2 read, 128 B/row
        };

        for (int w = 0; w < 16 && nsel <= sl; ++w) {
            unsigned long long m = ~__ballot((int)((sup >> w) & 1u));
            while (m != 0ull && nsel <= sl) {
                unsigned long long t = m;
                int k1 = __builtin_ctzll(t); t &= t - 1;
                bool h2 = t != 0; int k2 = h2 ? __builtin_ctzll(t) : k1; t &= t - 1;
                bool h3 = t != 0; int k3 = h3 ? __builtin_ctzll(t) : k1; t &= t - 1;
                bool h4 = t != 0; int k4 = h4 ? __builtin_ctzll(t) : k1;
                int g1 = (w << 6) + k1, g2 = (w << 6) + k2;
                int g3 = (w << 6) + k3, g4 = (w << 6) + k4;
                unsigned short r1 = ROW(g1), r2 = ROW(g2), r3 = ROW(g3), r4 = ROW(g4);
                if (nsel == sl) { kmine = g1; got = 1; }
                sup |= r1; nsel++;
                m = ~__ballot((int)((sup >> w) & 1u));
                if (h2 && nsel <= sl && ((m >> k2) & 1ull)) {
                    if (nsel == sl) { kmine = g2; got = 1; }
                    sup |= r2; nsel++;
                    m = ~__ballot((int)((sup >> w) & 1u));
                }
                if (h3 && nsel <= sl && ((m >> k3) & 1ull)) {
                    if (nsel == sl) { kmine = g3; got = 1; }
                    sup |= r3; nsel++;
                    m = ~__ballot((int)((sup >> w) & 1u));
                }
                if (h4 && nsel <= sl && ((m >> k4) & 1ull)) {
                    if (nsel == sl) { kmine = g4; got = 1; }
                    sup |= r4; nsel++;
                    m = ~__ballot((int)((sup >> w) & 1u));
                }
            }
        }
        __builtin_amdgcn_s_setprio(0);
        if (lane == 0) { res_k = kmine; res_vf = got ? 1.f : 0.f; }
    }
    __syncthreads();

    int k = res_k;
    float vf = res_vf;
    int gi = order[b * KPAD + k];

    if (tid == 0) {
        const float* bw = boxes_ws + (size_t)b * 6 * KPAD;
        float* ob = out_boxes + (size_t)s * 6;
#pragma unroll
        for (int c = 0; c < 6; ++c) ob[c] = bw[c * KPAD + k] * vf;
        out_bidx[s] = (float)b;
    }

    // ---- R12-proven row-gather trilinear resize (nt streaming loads/stores) ----
    const float* src = masks + (size_t)(b * NN + gi) * MASK_IN_VOX;
    float* dst = out_masks + (size_t)s * MASK_OUT_VOX;
    int lane = tid & 63;
    float* rb = rowbuf[tid >> 6];
    const f4* s4b = (const f4*)src;

#pragma unroll
    for (int p = 0; p < 4; ++p) {
        int idx = p * 256 + tid;
        int oy = idx & 31, oz = idx >> 5;

        float syf = 0.875f * oy - 0.0625f;
        int fly = (syf >= 0.f) ? (int)syf : -1;
        float fy = syf - (float)fly;
        int y0 = fly < 0 ? 0 : fly;
        int y1 = fly + 1 > 27 ? 27 : fly + 1;

        float szf = 0.875f * oz - 0.0625f;
        int flz = (szf >= 0.f) ? (int)szf : -1;
        float fz = szf - (float)flz;
        int z0 = flz < 0 ? 0 : flz;
        int z1 = flz + 1 > 27 ? 27 : flz + 1;

        float w00 = (1.f - fy) * (1.f - fz);
        float w01 = fy * (1.f - fz);
        float w10 = (1.f - fy) * fz;
        float w11 = fy * fz;

        const f4* r00 = s4b + (z0 * 28 + y0) * 7;
        const f4* r01 = s4b + (z0 * 28 + y1) * 7;
        const f4* r10 = s4b + (z1 * 28 + y0) * 7;
        const f4* r11 = s4b + (z1 * 28 + y1) * 7;

        float c[28];
#pragma unroll
        for (int t = 0; t < 7; ++t) {
            f4 a  = __builtin_nontemporal_load(r00 + t);
            f4 bb = __builtin_nontemporal_load(r01 + t);
            f4 cc = __builtin_nontemporal_load(r10 + t);
            f4 dd = __builtin_nontemporal_load(r11 + t);
            c[4 * t + 0] = a.x * w00 + bb.x * w01 + cc.x * w10 + dd.x * w11;
            c[4 * t + 1] = a.y * w00 + bb.y * w01 + cc.y * w10 + dd.y * w11;
            c[4 * t + 2] = a.z * w00 + bb.z * w01 + cc.z * w10 + dd.z * w11;
            c[4 * t + 3] = a.w * w00 + bb.w * w01 + cc.w * w10 + dd.w * w11;
        }

#pragma unroll
        for (int e = 0; e < 8; ++e) {
            float4 o;
#pragma unroll
            for (int qq = 0; qq < 4; ++qq) {
                const int ox = e * 4 + qq;
                const float sx = 0.875f * (float)ox - 0.0625f;
                const int flx = (ox == 0) ? -1 : (14 * ox - 1) / 16;
                const float fx = sx - (float)flx;
                const int x0 = flx < 0 ? 0 : flx;
                const int x1 = flx + 1 > 27 ? 27 : flx + 1;
                (&o.x)[qq] = (c[x0] + fx * (c[x1] - c[x0])) * vf;
            }
            *(float4*)&rb[lane * 36 + e * 4] = o;
        }

        f4* dchunk = (f4*)dst + (size_t)(p * 256 + (tid & ~63)) * 8;
#pragma unroll
        for (int t = 0; t < 8; ++t) {
            int f = t * 64 + lane;
            f4 v = *(const f4*)&rb[(f >> 3) * 36 + (f & 7) * 4];
            __builtin_nontemporal_store(v, dchunk + f);
        }
    }
}

// ---------------- launch ----------------------------------------------------
extern "C" void kernel_launch(void* const* d_in, const int* in_sizes, int n_in,
                              void* d_out, int out_size, void* d_ws, size_t ws_size,
                              hipStream_t stream) {
    const float* proposals = (const float*)d_in[0];
    const float* scores    = (const float*)d_in[1];
    const float* deltas    = (const float*)d_in[2];
    const float* masks     = (const float*)d_in[3];

    float* out = (float*)d_out;
    float* out_boxes = out;                                              // [512,6]
    float* out_masks = out + (size_t)BB * MAXOUT * 6;                    // [512,32768]
    float* out_bidx  = out + (size_t)BB * MAXOUT * 6 + (size_t)BB * MAXOUT * MASK_OUT_VOX;

    char* ws = (char*)d_ws;
    int*            order    = (int*)(ws);                               // 16 KB
    float*          boxes_ws = (float*)(ws + (20 << 10));                // 96 KB
    unsigned short* rowBits  = (unsigned short*)(ws + (116 << 10));      // 512 KB

    rank_kernel<<<BB * 32, 256, 0, stream>>>(scores, proposals, deltas, order, boxes_ws);
    build_kernel<<<dim3(64, BB), 256, 0, stream>>>(boxes_ws, rowBits);
    resize_walk_kernel<<<BB * MAXOUT, 256, 0, stream>>>(masks, rowBits, order, boxes_ws,
                                                        out_boxes, out_masks, out_bidx);
}

// Round 16
// 68.625 us; speedup vs baseline: 1.9351x; 1.9351x over previous
//
#include <hip/hip_runtime.h>
#include <stdint.h>

#define BB 4
#define NN 2000
#define K_PRE 1000
#define KPAD 1024
#define MAXOUT 128
#define NMS_THR 0.3f
#define MASK_IN_VOX (28*28*28)   // 21952
#define MASK_OUT_VOX (32*32*32)  // 32768

typedef float f4 __attribute__((ext_vector_type(4)));   // nontemporal-compatible

// ---------------- rank (stable descending argsort) + regression -------------
__global__ __launch_bounds__(256) void rank_kernel(const float* __restrict__ scores,
                                                   const float* __restrict__ proposals,
                                                   const float* __restrict__ deltas,
                                                   int* __restrict__ order,
                                                   float* __restrict__ boxes_ws) {
    int b = blockIdx.x >> 5;
    int blk = blockIdx.x & 31;
    __shared__ float s[NN];
    const float* sb = scores + b * NN;
    for (int u = threadIdx.x; u < NN / 4; u += 256)
        ((float4*)s)[u] = ((const float4*)sb)[u];
    __syncthreads();

    int i = blk * 64 + (threadIdx.x >> 2);
    int q = threadIdx.x & 3;
    float si = (i < NN) ? s[i] : 0.f;
    int cnt = 0;
    int j0 = q * 500;
    const float4* s4 = (const float4*)s;
#pragma unroll 5
    for (int u = 0; u < 125; ++u) {
        float4 v = s4[j0 / 4 + u];
        int j = j0 + u * 4;
        cnt += (v.x > si) + (v.y > si) + (v.z > si) + (v.w > si);
        cnt += ((v.x == si) & (j + 0 < i)) + ((v.y == si) & (j + 1 < i))
             + ((v.z == si) & (j + 2 < i)) + ((v.w == si) & (j + 3 < i));
    }
    cnt += __shfl_xor(cnt, 1);
    cnt += __shfl_xor(cnt, 2);

    if (q == 0 && i < NN && cnt < K_PRE) {
        int rank = cnt;
        order[b * KPAD + rank] = i;
        const float* p = proposals + (size_t)(b * NN + i) * 6;
        const float* d = deltas    + (size_t)(b * NN + i) * 6;
        float py1 = p[0], px1 = p[1], pz1 = p[2], py2 = p[3], px2 = p[4], pz2 = p[5];
        float h = py2 - py1, w = px2 - px1, dd = pz2 - pz1;
        float cy = py1 + 0.5f * h + d[0] * h;
        float cx = px1 + 0.5f * w + d[1] * w;
        float cz = pz1 + 0.5f * dd + d[2] * dd;
        h *= expf(d[3]); w *= expf(d[4]); dd *= expf(d[5]);
        float* bw = boxes_ws + (size_t)b * 6 * KPAD + rank;
        bw[0 * KPAD] = cy - 0.5f * h;  bw[1 * KPAD] = cx - 0.5f * w;  bw[2 * KPAD] = cz - 0.5f * dd;
        bw[3 * KPAD] = cy + 0.5f * h;  bw[4 * KPAD] = cx + 0.5f * w;  bw[5 * KPAD] = cz + 0.5f * dd;
    }
}

// ---------------- suppression bit-matrix build ------------------------------
// rowBits[(b*KPAD+k)*64+l] (uint16): bit w <=> IoU(box k, box 64w+l) > thr
__global__ __launch_bounds__(256) void build_kernel(const float* __restrict__ boxes_ws,
                                                    unsigned short* __restrict__ rowBits) {
    int b = blockIdx.y;
    int kbase = blockIdx.x * 16;
    __shared__ float sbx[6][1088];     // stride-17 padding: index k + (k>>4)
    int tid = threadIdx.x;
    const float* bw = boxes_ws + (size_t)b * 6 * KPAD;
    for (int k = tid; k < KPAD; k += 256) {
        int ks = k + (k >> 4);
#pragma unroll
        for (int c = 0; c < 6; ++c) sbx[c][ks] = bw[c * KPAD + k];
    }
    __syncthreads();
    int l = tid & 63, lr = tid >> 6;
#pragma unroll
    for (int pss = 0; pss < 4; ++pss) {
        int k = kbase + pss * 4 + lr;
        int ks = k + (k >> 4);
        float ry1 = sbx[0][ks], rx1 = sbx[1][ks], rz1 = sbx[2][ks];
        float ry2 = sbx[3][ks], rx2 = sbx[4][ks], rz2 = sbx[5][ks];
        float v1 = (ry2 - ry1) * (rx2 - rx1) * (rz2 - rz1);
        uint32_t bits = 0;
#pragma unroll
        for (int w = 0; w < 16; ++w) {
            int j = 64 * w + l;
            int js = j + (j >> 4);
            float y1 = sbx[0][js], x1 = sbx[1][js], z1 = sbx[2][js];
            float y2 = sbx[3][js], x2 = sbx[4][js], z2 = sbx[5][js];
            float iy = fmaxf(fminf(ry2, y2) - fmaxf(ry1, y1), 0.f);
            float ix = fmaxf(fminf(rx2, x2) - fmaxf(rx1, x1), 0.f);
            float iz = fmaxf(fminf(rz2, z2) - fmaxf(rz1, z1), 0.f);
            float inter = iy * ix * iz;
            float v2 = (y2 - y1) * (x2 - x1) * (z2 - z1);
            float iou = inter / (v1 + v2 - inter + 1e-8f);
            bits |= (iou > NMS_THR ? 1u : 0u) << w;
        }
        if (k < K_PRE)
            rowBits[((size_t)(b * KPAD + k)) * 64 + l] = (unsigned short)bits;
    }
}

// ---------------- fused walk+resize (R12-proven; nt on output stores only) --
__global__ __launch_bounds__(256) void resize_walk_kernel(
        const float* __restrict__ masks,
        const unsigned short* __restrict__ rowBits,
        const int* __restrict__ order,
        const float* __restrict__ boxes_ws,
        float* __restrict__ out_boxes,
        float* __restrict__ out_masks,
        float* __restrict__ out_bidx) {
    int s = blockIdx.x;            // 0..511
    int b = s >> 7;
    int sl = s & 127;              // which pick this block owns
    int tid = threadIdx.x;

    __shared__ int   res_k;
    __shared__ float res_vf;
    __shared__ __align__(16) float rowbuf[4][64 * 36];

    if (tid < 64) {
        int lane = tid;
        const unsigned short* rowB = rowBits + (size_t)b * KPAD * 64;
        uint32_t sup = (lane >= 40) ? (1u << 15) : 0u;   // pads >=1000 pre-suppressed
        int nsel = 0, kmine = 0, got = 0;

        auto ROW = [&](int g) -> unsigned short {
            return rowB[((size_t)g << 6) + lane];        // L2 read, 128 B/row
        };

        for (int w = 0; w < 16 && nsel <= sl; ++w) {
            unsigned long long m = ~__ballot((int)((sup >> w) & 1u));
            while (m != 0ull && nsel <= sl) {
                unsigned long long t = m;
                int k1 = __builtin_ctzll(t); t &= t - 1;
                bool h2 = t != 0; int k2 = h2 ? __builtin_ctzll(t) : k1; t &= t - 1;
                bool h3 = t != 0; int k3 = h3 ? __builtin_ctzll(t) : k1; t &= t - 1;
                bool h4 = t != 0; int k4 = h4 ? __builtin_ctzll(t) : k1;
                int g1 = (w << 6) + k1, g2 = (w << 6) + k2;
                int g3 = (w << 6) + k3, g4 = (w << 6) + k4;
                unsigned short r1 = ROW(g1), r2 = ROW(g2), r3 = ROW(g3), r4 = ROW(g4);
                if (nsel == sl) { kmine = g1; got = 1; }
                sup |= r1; nsel++;
                m = ~__ballot((int)((sup >> w) & 1u));
                if (h2 && nsel <= sl && ((m >> k2) & 1ull)) {
                    if (nsel == sl) { kmine = g2; got = 1; }
                    sup |= r2; nsel++;
                    m = ~__ballot((int)((sup >> w) & 1u));
                }
                if (h3 && nsel <= sl && ((m >> k3) & 1ull)) {
                    if (nsel == sl) { kmine = g3; got = 1; }
                    sup |= r3; nsel++;
                    m = ~__ballot((int)((sup >> w) & 1u));
                }
                if (h4 && nsel <= sl && ((m >> k4) & 1ull)) {
                    if (nsel == sl) { kmine = g4; got = 1; }
                    sup |= r4; nsel++;
                    m = ~__ballot((int)((sup >> w) & 1u));
                }
            }
        }
        if (lane == 0) { res_k = kmine; res_vf = got ? 1.f : 0.f; }
    }
    __syncthreads();

    int k = res_k;
    float vf = res_vf;
    int gi = order[b * KPAD + k];

    if (tid == 0) {
        const float* bw = boxes_ws + (size_t)b * 6 * KPAD;
        float* ob = out_boxes + (size_t)s * 6;
#pragma unroll
        for (int c = 0; c < 6; ++c) ob[c] = bw[c * KPAD + k] * vf;
        out_bidx[s] = (float)b;
    }

    // ---- R12-proven row-gather trilinear resize (normal L1-cached loads) ----
    const float* src = masks + (size_t)(b * NN + gi) * MASK_IN_VOX;
    float* dst = out_masks + (size_t)s * MASK_OUT_VOX;
    int lane = tid & 63;
    float* rb = rowbuf[tid >> 6];
    const float4* s4b = (const float4*)src;

#pragma unroll
    for (int p = 0; p < 4; ++p) {
        int idx = p * 256 + tid;
        int oy = idx & 31, oz = idx >> 5;

        float syf = 0.875f * oy - 0.0625f;
        int fly = (syf >= 0.f) ? (int)syf : -1;
        float fy = syf - (float)fly;
        int y0 = fly < 0 ? 0 : fly;
        int y1 = fly + 1 > 27 ? 27 : fly + 1;

        float szf = 0.875f * oz - 0.0625f;
        int flz = (szf >= 0.f) ? (int)szf : -1;
        float fz = szf - (float)flz;
        int z0 = flz < 0 ? 0 : flz;
        int z1 = flz + 1 > 27 ? 27 : flz + 1;

        float w00 = (1.f - fy) * (1.f - fz);
        float w01 = fy * (1.f - fz);
        float w10 = (1.f - fy) * fz;
        float w11 = fy * fz;

        const float4* r00 = s4b + (z0 * 28 + y0) * 7;
        const float4* r01 = s4b + (z0 * 28 + y1) * 7;
        const float4* r10 = s4b + (z1 * 28 + y0) * 7;
        const float4* r11 = s4b + (z1 * 28 + y1) * 7;

        float c[28];
#pragma unroll
        for (int t = 0; t < 7; ++t) {
            float4 a = r00[t], bb = r01[t], cc = r10[t], dd = r11[t];
            c[4 * t + 0] = a.x * w00 + bb.x * w01 + cc.x * w10 + dd.x * w11;
            c[4 * t + 1] = a.y * w00 + bb.y * w01 + cc.y * w10 + dd.y * w11;
            c[4 * t + 2] = a.z * w00 + bb.z * w01 + cc.z * w10 + dd.z * w11;
            c[4 * t + 3] = a.w * w00 + bb.w * w01 + cc.w * w10 + dd.w * w11;
        }

#pragma unroll
        for (int e = 0; e < 8; ++e) {
            float4 o;
#pragma unroll
            for (int qq = 0; qq < 4; ++qq) {
                const int ox = e * 4 + qq;
                const float sx = 0.875f * (float)ox - 0.0625f;
                const int flx = (ox == 0) ? -1 : (14 * ox - 1) / 16;
                const float fx = sx - (float)flx;
                const int x0 = flx < 0 ? 0 : flx;
                const int x1 = flx + 1 > 27 ? 27 : flx + 1;
                (&o.x)[qq] = (c[x0] + fx * (c[x1] - c[x0])) * vf;
            }
            *(float4*)&rb[lane * 36 + e * 4] = o;
        }

        // coalesced copy-out; nt store: output is write-once, never re-read here
        f4* dchunk = (f4*)dst + (size_t)(p * 256 + (tid & ~63)) * 8;
#pragma unroll
        for (int t = 0; t < 8; ++t) {
            int f = t * 64 + lane;
            f4 v = *(const f4*)&rb[(f >> 3) * 36 + (f & 7) * 4];
            __builtin_nontemporal_store(v, dchunk + f);
        }
    }
}

// ---------------- launch ----------------------------------------------------
extern "C" void kernel_launch(void* const* d_in, const int* in_sizes, int n_in,
                              void* d_out, int out_size, void* d_ws, size_t ws_size,
                              hipStream_t stream) {
    const float* proposals = (const float*)d_in[0];
    const float* scores    = (const float*)d_in[1];
    const float* deltas    = (const float*)d_in[2];
    const float* masks     = (const float*)d_in[3];

    float* out = (float*)d_out;
    float* out_boxes = out;                                              // [512,6]
    float* out_masks = out + (size_t)BB * MAXOUT * 6;                    // [512,32768]
    float* out_bidx  = out + (size_t)BB * MAXOUT * 6 + (size_t)BB * MAXOUT * MASK_OUT_VOX;

    char* ws = (char*)d_ws;
    int*            order    = (int*)(ws);                               // 16 KB
    float*          boxes_ws = (float*)(ws + (20 << 10));                // 96 KB
    unsigned short* rowBits  = (unsigned short*)(ws + (116 << 10));      // 512 KB

    rank_kernel<<<BB * 32, 256, 0, stream>>>(scores, proposals, deltas, order, boxes_ws);
    build_kernel<<<dim3(64, BB), 256, 0, stream>>>(boxes_ws, rowBits);
    resize_walk_kernel<<<BB * MAXOUT, 256, 0, stream>>>(masks, rowBits, order, boxes_ws,
                                                        out_boxes, out_masks, out_bidx);
}